// Round 9
// baseline (336.914 us; speedup 1.0000x reference)
//
#include <hip/hip_runtime.h>

#define HEADS 16
#define DHEAD 64
#define BATCH 2
#define SEQ   2048
#define DIM   1024
#define ROWS  (BATCH*SEQ)      // 4096
#define SCALE_LOG2E 0.180336880f   // 0.125 * log2(e)

typedef short v8s __attribute__((ext_vector_type(8)));
typedef float v4f __attribute__((ext_vector_type(4)));

__device__ __forceinline__ float fast_exp2(float x) {
    return __builtin_amdgcn_exp2f(x);   // v_exp_f32: D = 2^S0
}

__device__ __forceinline__ unsigned short f2bf(float f) {
    unsigned u = __float_as_uint(f);
    u += 0x7FFFu + ((u >> 16) & 1u);   // RNE
    return (unsigned short)(u >> 16);
}

// pack two f32 -> bf16x2 dword (truncation): low short = bf(lo), high = bf(hi)
__device__ __forceinline__ unsigned pk_bf2(float hi, float lo) {
    return __builtin_amdgcn_perm(__float_as_uint(hi), __float_as_uint(lo), 0x07060302u);
}

// async global->LDS, 16B per lane (LDS dst = wave-uniform base + lane*16)
#define GLDS16(g, l) __builtin_amdgcn_global_load_lds( \
    (__attribute__((address_space(1))) void*)(g), \
    (__attribute__((address_space(3))) void*)(l), 16, 0, 0)

// ---------------- Fused LayerNorm + weight transpose (one launch) ----------------
__global__ __launch_bounds__(256) void ln_tr_kernel(const float* __restrict__ x,
                                                    const float* __restrict__ gamma,
                                                    const float* __restrict__ beta,
                                                    unsigned short* __restrict__ xn,
                                                    const float* __restrict__ Wqk,
                                                    const float* __restrict__ Wv,
                                                    const float* __restrict__ Wout,
                                                    unsigned short* __restrict__ Tqk,
                                                    unsigned short* __restrict__ Tv,
                                                    unsigned short* __restrict__ To) {
    int bid = blockIdx.x;
    int t = threadIdx.x;
    if (bid < ROWS) {
        const float* xr = x + (size_t)bid * DIM;
        float4 v = *(const float4*)(xr + t * 4);
        float s  = v.x + v.y + v.z + v.w;
        float sq = v.x * v.x + v.y * v.y + v.z * v.z + v.w * v.w;
#pragma unroll
        for (int off = 32; off > 0; off >>= 1) {
            s  += __shfl_down(s,  off, 64);
            sq += __shfl_down(sq, off, 64);
        }
        __shared__ float ss[4], ssq[4];
        int wave = t >> 6, lane = t & 63;
        if (lane == 0) { ss[wave] = s; ssq[wave] = sq; }
        __syncthreads();
        float tot  = ss[0] + ss[1] + ss[2] + ss[3];
        float totq = ssq[0] + ssq[1] + ssq[2] + ssq[3];
        float mean = tot * (1.f / DIM);
        float var  = totq * (1.f / DIM) - mean * mean;
        float rstd = rsqrtf(var + 1e-5f);
        float4 g = *(const float4*)(gamma + t * 4);
        float4 bb = *(const float4*)(beta + t * 4);
        ushort4 o;
        o.x = f2bf((v.x - mean) * rstd * g.x + bb.x);
        o.y = f2bf((v.y - mean) * rstd * g.y + bb.y);
        o.z = f2bf((v.z - mean) * rstd * g.z + bb.z);
        o.w = f2bf((v.w - mean) * rstd * g.w + bb.w);
        *(ushort4*)(xn + (size_t)bid * DIM + t * 4) = o;
    } else {
        int tb = bid - ROWS;            // 0..1023
        int z, bx, by;
        if (tb < 512) { z = 0; bx = tb & 31; by = tb >> 5; }
        else { int t2 = tb - 512; z = 1 + (t2 >> 8); int r = t2 & 255; bx = r & 15; by = r >> 4; }
        const float* W = (z == 0) ? Wqk : (z == 1) ? Wv : Wout;
        unsigned short* Wt = (z == 0) ? Tqk : (z == 1) ? Tv : To;
        int Nw = (z == 0) ? 2048 : 1024;
        int n0 = bx * 64, k0 = by * 64;
        __shared__ float tile[64][65];
#pragma unroll
        for (int l = 0; l < 4; ++l) {
            int kk = (t >> 4) + l * 16;
            int nn = (t & 15) * 4;
            float4 v = *(const float4*)(W + (size_t)(k0 + kk) * Nw + n0 + nn);
            tile[kk][nn + 0] = v.x; tile[kk][nn + 1] = v.y;
            tile[kk][nn + 2] = v.z; tile[kk][nn + 3] = v.w;
        }
        __syncthreads();
#pragma unroll
        for (int l = 0; l < 4; ++l) {
            int cid = t + l * 256;
            int nn = cid >> 4, kc = (cid & 15) * 4;
            ushort4 o;
            o.x = f2bf(tile[kc + 0][nn]);
            o.y = f2bf(tile[kc + 1][nn]);
            o.z = f2bf(tile[kc + 2][nn]);
            o.w = f2bf(tile[kc + 3][nn]);
            *(ushort4*)(Wt + (size_t)(n0 + nn) * DIM + k0 + kc) = o;
        }
    }
}

// ---------------- LDS-staged MFMA GEMM core with global_load_lds ----------------
// BM=128, BK=32. LDS unpadded [rows][32] shorts (64B rows) so lane*16B is linear.
template<int BN, bool SWAP>
__device__ __forceinline__ void mm_core2(const unsigned short* __restrict__ A,
                                         const unsigned short* __restrict__ Bt,
                                         int K, int aTile, int bTile,
                                         unsigned short (*As)[32],
                                         unsigned short (*Bs)[32],
                                         v4f (*acc)[4]) {
    constexpr int MI = (BN == 128) ? 4 : 2;
    int t = threadIdx.x;
    int w = t >> 6, L = t & 63, l15 = L & 15, quad = L >> 4;
    int aOff = (BN == 128) ? (w >> 1) * 64 : w * 32;
    int bOff = (BN == 128) ? (w & 1) * 64 : 0;
    int srow = L >> 2, schunk = (L & 3) * 8;   // staging: 4 lanes per row
    for (int k0 = 0; k0 < K; k0 += 32) {
        __syncthreads();    // previous tile fully consumed
#pragma unroll
        for (int j = 0; j < 2; ++j) {
            int g = w * 2 + j;
            GLDS16(A + (size_t)(aTile + g * 16 + srow) * K + k0 + schunk,
                   &As[g * 16][0]);
        }
#pragma unroll
        for (int j = 0; j < BN / 64; ++j) {
            int g = (BN == 128) ? (w * 2 + j) : w;
            GLDS16(Bt + (size_t)(bTile + g * 16 + srow) * K + k0 + schunk,
                   &Bs[g * 16][0]);
        }
        __syncthreads();    // drains vmcnt: staged tile visible
        v8s a[MI], b[4];
#pragma unroll
        for (int i = 0; i < MI; ++i) a[i] = *(const v8s*)&As[aOff + i * 16 + l15][quad * 8];
#pragma unroll
        for (int j = 0; j < 4; ++j) b[j] = *(const v8s*)&Bs[bOff + j * 16 + l15][quad * 8];
#pragma unroll
        for (int i = 0; i < MI; ++i)
#pragma unroll
            for (int j = 0; j < 4; ++j)
                acc[i][j] = SWAP
                    ? __builtin_amdgcn_mfma_f32_16x16x32_bf16(b[j], a[i], acc[i][j], 0, 0, 0)
                    : __builtin_amdgcn_mfma_f32_16x16x32_bf16(a[i], b[j], acc[i][j], 0, 0, 0);
    }
}

// ---------------- Fused GEMM -> q_h [b][h][seq][64] + K/V in MFMA-FRAGMENT order --
// k_frag/v_frag layout: [bh][tile(32)][region(8)][lane(64)][8 shorts]
__global__ __launch_bounds__(256) void gemm_qkv_kernel(const unsigned short* __restrict__ A,
                                                       const unsigned short* __restrict__ Bt,
                                                       unsigned short* __restrict__ q_h,
                                                       unsigned short* __restrict__ k_frag,
                                                       unsigned short* __restrict__ v_frag) {
    __shared__ __align__(16) unsigned short As[128][32];
    __shared__ __align__(16) unsigned short Bs[128][32];
    int t = threadIdx.x, w = t >> 6, L = t & 63, l15 = L & 15, quad = L >> 4;
    int aTile = blockIdx.y * 128, bTile = blockIdx.x * 128;
    int aOff = (w >> 1) * 64, bOff = (w & 1) * 64;
    v4f acc[4][4] = {};
    if (bTile < 2048) {
        mm_core2<128, true>(A, Bt, DIM, aTile, bTile, As, Bs, acc);
        float sc = (bTile < 1024) ? SCALE_LOG2E : 1.0f;   // uniform per block
#pragma unroll
        for (int j = 0; j < 4; ++j) {
            int col = bTile + bOff + j * 16 + quad * 4;   // 4 consecutive d
            int c = col & 1023;
            int h = c >> 6, d = c & 63;
            int half = d >> 5, Lhi = (d >> 3) & 3, jj = d & 7;
#pragma unroll
            for (int i = 0; i < 4; ++i) {
                int m = aTile + aOff + i * 16 + l15;
                int b = m >> 11, seq = m & 2047;
                ushort4 o;
                o.x = f2bf(acc[i][j][0] * sc); o.y = f2bf(acc[i][j][1] * sc);
                o.z = f2bf(acc[i][j][2] * sc); o.w = f2bf(acc[i][j][3] * sc);
                if (col < 1024) {
                    *(ushort4*)(q_h + (((size_t)(b * 16 + h)) * SEQ + seq) * 64 + d) = o;
                } else {
                    int kT = seq >> 6, jt = (seq >> 4) & 3, L15 = seq & 15;
                    size_t off = ((((size_t)(b * 16 + h) * 32 + kT) * 8 + (jt * 2 + half)) * 64
                                  + (Lhi * 16 + L15)) * 8 + jj;
                    *(ushort4*)(k_frag + off) = o;
                }
            }
        }
    } else {
        mm_core2<128, false>(A, Bt, DIM, aTile, bTile, As, Bs, acc);
#pragma unroll
        for (int j = 0; j < 4; ++j) {
            int c = bTile + bOff + j * 16 + l15 - 2048;
            int h = c >> 6, d = c & 63;
            int dt = d >> 4, L15v = d & 15;
#pragma unroll
            for (int i = 0; i < 4; ++i) {
                int m0 = aTile + aOff + i * 16 + quad * 4;   // 4 consecutive seq
                int b = m0 >> 11, seq0 = m0 & 2047;
                int vT = seq0 >> 6, half = (seq0 >> 5) & 1, Lhi = (seq0 >> 3) & 3, jv = seq0 & 7;
                ushort4 o;
                o.x = f2bf(acc[i][j][0]); o.y = f2bf(acc[i][j][1]);
                o.z = f2bf(acc[i][j][2]); o.w = f2bf(acc[i][j][3]);
                size_t off = ((((size_t)(b * 16 + h) * 32 + vT) * 8 + (dt * 2 + half)) * 64
                              + (Lhi * 16 + L15v)) * 8 + jv;
                *(ushort4*)(v_frag + off) = o;
            }
        }
    }
}

// ---------------- Final GEMM + bias, f32 out (BN=64, BK=32, C^T) ------
__global__ __launch_bounds__(256) void gemm_out_kernel(const unsigned short* __restrict__ A,
                                                       const unsigned short* __restrict__ Bt,
                                                       const float* __restrict__ bias,
                                                       float* __restrict__ C) {
    __shared__ __align__(16) unsigned short As[128][32];
    __shared__ __align__(16) unsigned short Bs[64][32];
    int t = threadIdx.x, w = t >> 6, L = t & 63, l15 = L & 15, quad = L >> 4;
    int aTile = blockIdx.y * 128, bTile = blockIdx.x * 64;
    v4f acc[2][4] = {};
    mm_core2<64, true>(A, Bt, DIM, aTile, bTile, As, Bs, acc);
#pragma unroll
    for (int j = 0; j < 4; ++j) {
        int n = bTile + j * 16 + quad * 4;    // 4 consecutive cols
        float4 bv = *(const float4*)(bias + n);
#pragma unroll
        for (int i = 0; i < 2; ++i) {
            int m = aTile + w * 32 + i * 16 + l15;
            float4 o = make_float4(acc[i][j][0] + bv.x, acc[i][j][1] + bv.y,
                                   acc[i][j][2] + bv.z, acc[i][j][3] + bv.w);
            *(float4*)(C + (size_t)m * DIM + n) = o;
        }
    }
}

// ---------------- MFMA flash attention v9: fragment-direct, 16 Q-rows/wave ------
// v8's barrier-free fragment-direct structure, wave granularity halved:
// 1024 blocks (4/CU) x 4 waves x 16 Q rows -> 16 waves/CU = 4/SIMD (2x v8 TLP).
// Per-wave chain halves (no m-loop); 4 independent chains per SIMD hide latency.
// All 4 waves/block read identical K/V fragment addresses -> L1-served.
__global__ __launch_bounds__(256, 4) void attn_kernel(const unsigned short* __restrict__ q_h,
                                                      const unsigned short* __restrict__ k_frag,
                                                      const unsigned short* __restrict__ v_frag,
                                                      unsigned short* __restrict__ ao) {
    __shared__ __align__(16) unsigned short Pld[4][16 * 72];   // 9 KB, wave-private
    int bid = blockIdx.x;
    int wg = (bid & 7) * 128 + (bid >> 3);   // XCD-contiguous remap (1024 = 8*128)
    int qt = wg & 31, h = (wg >> 5) & 15, b = wg >> 9;
    int bh = b * HEADS + h;
    int w = threadIdx.x >> 6;
    int L = threadIdx.x & 63, l15 = L & 15, quad = L >> 4;

    // wave w: q rows qt*64 + w*16 + l15
    const unsigned short* qp = q_h + ((size_t)bh * SEQ + qt * 64 + w * 16 + l15) * 64 + quad * 8;
    v8s qf0 = *(const v8s*)(qp);
    v8s qf1 = *(const v8s*)(qp + 32);

    // per-lane fragment bases: tile stride 4096 shorts, region stride 512
    const unsigned short* kb = k_frag + (size_t)bh * 32 * 4096 + (size_t)L * 8;
    const unsigned short* vb = v_frag + (size_t)bh * 32 * 4096 + (size_t)L * 8;

    v4f o[4] = {};
    v4f lacc = {};
    const short ob = (short)0x3F80;   // bf16 1.0
    const v8s ones = {ob, ob, ob, ob, ob, ob, ob, ob};

    v8s kA[4][2], kB[4][2], vf[4][2];
    // prologue: kf tile 0 -> kA
#pragma unroll
    for (int jt = 0; jt < 4; ++jt) {
        kA[jt][0] = *(const v8s*)(kb + (jt * 2 + 0) * 512);
        kA[jt][1] = *(const v8s*)(kb + (jt * 2 + 1) * 512);
    }

#define ATTN_BODY(T, KC, KN)                                                          \
    {                                                                                 \
        const unsigned short* vt_ = vb + (size_t)(T) * 4096;                          \
        _Pragma("unroll")                                                             \
        for (int dt = 0; dt < 4; ++dt) {                                              \
            vf[dt][0] = *(const v8s*)(vt_ + (dt * 2 + 0) * 512);                      \
            vf[dt][1] = *(const v8s*)(vt_ + (dt * 2 + 1) * 512);                      \
        }                                                                             \
        if ((T) + 1 < SEQ / 64) {                                                     \
            const unsigned short* kt_ = kb + (size_t)((T) + 1) * 4096;                \
            _Pragma("unroll")                                                         \
            for (int jt = 0; jt < 4; ++jt) {                                          \
                KN[jt][0] = *(const v8s*)(kt_ + (jt * 2 + 0) * 512);                  \
                KN[jt][1] = *(const v8s*)(kt_ + (jt * 2 + 1) * 512);                  \
            }                                                                         \
        }                                                                             \
        v4f s[4] = {};                                                                \
        __builtin_amdgcn_s_setprio(1);                                                \
        _Pragma("unroll")                                                             \
        for (int jt = 0; jt < 4; ++jt) {                                              \
            s[jt] = __builtin_amdgcn_mfma_f32_16x16x32_bf16(KC[jt][0], qf0, s[jt], 0, 0, 0); \
            s[jt] = __builtin_amdgcn_mfma_f32_16x16x32_bf16(KC[jt][1], qf1, s[jt], 0, 0, 0); \
        }                                                                             \
        __builtin_amdgcn_s_setprio(0);                                                \
        _Pragma("unroll")                                                             \
        for (int jt = 0; jt < 4; ++jt) {                                              \
            float p0 = fast_exp2(s[jt][0]);                                           \
            float p1 = fast_exp2(s[jt][1]);                                           \
            float p2 = fast_exp2(s[jt][2]);                                           \
            float p3 = fast_exp2(s[jt][3]);                                           \
            uint2 pk;                                                                 \
            pk.x = pk_bf2(p1, p0);                                                    \
            pk.y = pk_bf2(p3, p2);                                                    \
            *(uint2*)&Pld[w][l15 * 72 + jt * 16 + quad * 4] = pk;                     \
        }                                                                             \
        v8s pb0 = *(const v8s*)&Pld[w][l15 * 72 + quad * 8];                          \
        v8s pb1 = *(const v8s*)&Pld[w][l15 * 72 + 32 + quad * 8];                     \
        __builtin_amdgcn_s_setprio(1);                                                \
        _Pragma("unroll")                                                             \
        for (int dt = 0; dt < 4; ++dt) {                                              \
            o[dt] = __builtin_amdgcn_mfma_f32_16x16x32_bf16(vf[dt][0], pb0, o[dt], 0, 0, 0); \
            o[dt] = __builtin_amdgcn_mfma_f32_16x16x32_bf16(vf[dt][1], pb1, o[dt], 0, 0, 0); \
        }                                                                             \
        lacc = __builtin_amdgcn_mfma_f32_16x16x32_bf16(ones, pb0, lacc, 0, 0, 0);     \
        lacc = __builtin_amdgcn_mfma_f32_16x16x32_bf16(ones, pb1, lacc, 0, 0, 0);     \
        __builtin_amdgcn_s_setprio(0);                                                \
    }

    for (int t = 0; t < SEQ / 64; t += 2) {
        ATTN_BODY(t, kA, kB);
        ATTN_BODY(t + 1, kB, kA);
    }
#undef ATTN_BODY

    float inv = 1.f / lacc[0];
    int rowg = b * SEQ + qt * 64 + w * 16 + l15;
#pragma unroll
    for (int dt = 0; dt < 4; ++dt) {
        ushort4 ov;
        ov.x = f2bf(o[dt][0] * inv);
        ov.y = f2bf(o[dt][1] * inv);
        ov.z = f2bf(o[dt][2] * inv);
        ov.w = f2bf(o[dt][3] * inv);
        *(ushort4*)(ao + (size_t)rowg * DIM + h * 64 + dt * 16 + quad * 4) = ov;
    }
}

extern "C" void kernel_launch(void* const* d_in, const int* in_sizes, int n_in,
                              void* d_out, int out_size, void* d_ws, size_t ws_size,
                              hipStream_t stream) {
    const float* x     = (const float*)d_in[0];
    const float* gamma = (const float*)d_in[1];
    const float* beta  = (const float*)d_in[2];
    const float* Wqk   = (const float*)d_in[3];
    const float* Wv    = (const float*)d_in[4];
    const float* Wout  = (const float*)d_in[5];
    const float* bout  = (const float*)d_in[6];
    float* out = (float*)d_out;

    unsigned short* ws = (unsigned short*)d_ws;
    unsigned short* xn     = ws;                            // 4096*1024
    unsigned short* Wt_qk  = xn + (size_t)ROWS * DIM;       // 2048*1024
    unsigned short* Wt_v   = Wt_qk + (size_t)2048 * DIM;    // 1024*1024 (contiguous after qk)
    unsigned short* Wt_o   = Wt_v + (size_t)DIM * DIM;      // 1024*1024
    unsigned short* q_h    = Wt_o + (size_t)DIM * DIM;      // 4096*1024
    unsigned short* k_frag = q_h + (size_t)ROWS * DIM;      // 4096*1024 (fragment order)
    unsigned short* v_frag = k_frag + (size_t)ROWS * DIM;   // 4096*1024 (fragment order)
    unsigned short* ao     = v_frag + (size_t)ROWS * DIM;   // 4096*1024

    ln_tr_kernel<<<ROWS + 1024, 256, 0, stream>>>(x, gamma, beta, xn,
                                                  Wqk, Wv, Wout, Wt_qk, Wt_v, Wt_o);
    gemm_qkv_kernel<<<dim3(3072 / 128, ROWS / 128), 256, 0, stream>>>(xn, Wt_qk, q_h, k_frag, v_frag);
    attn_kernel<<<dim3(SEQ / 64 * HEADS * BATCH), 256, 0, stream>>>(q_h, k_frag, v_frag, ao);
    gemm_out_kernel<<<dim3(DIM / 64, ROWS / 128), 256, 0, stream>>>(ao, Wt_o, bout, out);
}

// Round 10
// 185.762 us; speedup vs baseline: 1.8137x; 1.8137x over previous
//
#include <hip/hip_runtime.h>

#define HEADS 16
#define DHEAD 64
#define BATCH 2
#define SEQ   2048
#define DIM   1024
#define ROWS  (BATCH*SEQ)      // 4096
#define SCALE_LOG2E 0.180336880f   // 0.125 * log2(e)

typedef short v8s __attribute__((ext_vector_type(8)));
typedef float v4f __attribute__((ext_vector_type(4)));

__device__ __forceinline__ float fast_exp2(float x) {
    return __builtin_amdgcn_exp2f(x);   // v_exp_f32: D = 2^S0
}

__device__ __forceinline__ unsigned short f2bf(float f) {
    unsigned u = __float_as_uint(f);
    u += 0x7FFFu + ((u >> 16) & 1u);   // RNE
    return (unsigned short)(u >> 16);
}

// pack two f32 -> bf16x2 dword (truncation): low short = bf(lo), high = bf(hi)
__device__ __forceinline__ unsigned pk_bf2(float hi, float lo) {
    return __builtin_amdgcn_perm(__float_as_uint(hi), __float_as_uint(lo), 0x07060302u);
}

// async global->LDS, 16B per lane (LDS dst = wave-uniform base + lane*16)
#define GLDS16(g, l) __builtin_amdgcn_global_load_lds( \
    (__attribute__((address_space(1))) void*)(g), \
    (__attribute__((address_space(3))) void*)(l), 16, 0, 0)

// ---------------- Fused LayerNorm + weight transpose (one launch) ----------------
__global__ __launch_bounds__(256) void ln_tr_kernel(const float* __restrict__ x,
                                                    const float* __restrict__ gamma,
                                                    const float* __restrict__ beta,
                                                    unsigned short* __restrict__ xn,
                                                    const float* __restrict__ Wqk,
                                                    const float* __restrict__ Wv,
                                                    const float* __restrict__ Wout,
                                                    unsigned short* __restrict__ Tqk,
                                                    unsigned short* __restrict__ Tv,
                                                    unsigned short* __restrict__ To) {
    int bid = blockIdx.x;
    int t = threadIdx.x;
    if (bid < ROWS) {
        const float* xr = x + (size_t)bid * DIM;
        float4 v = *(const float4*)(xr + t * 4);
        float s  = v.x + v.y + v.z + v.w;
        float sq = v.x * v.x + v.y * v.y + v.z * v.z + v.w * v.w;
#pragma unroll
        for (int off = 32; off > 0; off >>= 1) {
            s  += __shfl_down(s,  off, 64);
            sq += __shfl_down(sq, off, 64);
        }
        __shared__ float ss[4], ssq[4];
        int wave = t >> 6, lane = t & 63;
        if (lane == 0) { ss[wave] = s; ssq[wave] = sq; }
        __syncthreads();
        float tot  = ss[0] + ss[1] + ss[2] + ss[3];
        float totq = ssq[0] + ssq[1] + ssq[2] + ssq[3];
        float mean = tot * (1.f / DIM);
        float var  = totq * (1.f / DIM) - mean * mean;
        float rstd = rsqrtf(var + 1e-5f);
        float4 g = *(const float4*)(gamma + t * 4);
        float4 bb = *(const float4*)(beta + t * 4);
        ushort4 o;
        o.x = f2bf((v.x - mean) * rstd * g.x + bb.x);
        o.y = f2bf((v.y - mean) * rstd * g.y + bb.y);
        o.z = f2bf((v.z - mean) * rstd * g.z + bb.z);
        o.w = f2bf((v.w - mean) * rstd * g.w + bb.w);
        *(ushort4*)(xn + (size_t)bid * DIM + t * 4) = o;
    } else {
        int tb = bid - ROWS;            // 0..1023
        int z, bx, by;
        if (tb < 512) { z = 0; bx = tb & 31; by = tb >> 5; }
        else { int t2 = tb - 512; z = 1 + (t2 >> 8); int r = t2 & 255; bx = r & 15; by = r >> 4; }
        const float* W = (z == 0) ? Wqk : (z == 1) ? Wv : Wout;
        unsigned short* Wt = (z == 0) ? Tqk : (z == 1) ? Tv : To;
        int Nw = (z == 0) ? 2048 : 1024;
        int n0 = bx * 64, k0 = by * 64;
        __shared__ float tile[64][65];
#pragma unroll
        for (int l = 0; l < 4; ++l) {
            int kk = (t >> 4) + l * 16;
            int nn = (t & 15) * 4;
            float4 v = *(const float4*)(W + (size_t)(k0 + kk) * Nw + n0 + nn);
            tile[kk][nn + 0] = v.x; tile[kk][nn + 1] = v.y;
            tile[kk][nn + 2] = v.z; tile[kk][nn + 3] = v.w;
        }
        __syncthreads();
#pragma unroll
        for (int l = 0; l < 4; ++l) {
            int cid = t + l * 256;
            int nn = cid >> 4, kc = (cid & 15) * 4;
            ushort4 o;
            o.x = f2bf(tile[kc + 0][nn]);
            o.y = f2bf(tile[kc + 1][nn]);
            o.z = f2bf(tile[kc + 2][nn]);
            o.w = f2bf(tile[kc + 3][nn]);
            *(ushort4*)(Wt + (size_t)(n0 + nn) * DIM + k0 + kc) = o;
        }
    }
}

// ---------------- LDS-staged MFMA GEMM core with global_load_lds ----------------
// BM=128, BK=32. LDS unpadded [rows][32] shorts (64B rows) so lane*16B is linear.
template<int BN, bool SWAP>
__device__ __forceinline__ void mm_core2(const unsigned short* __restrict__ A,
                                         const unsigned short* __restrict__ Bt,
                                         int K, int aTile, int bTile,
                                         unsigned short (*As)[32],
                                         unsigned short (*Bs)[32],
                                         v4f (*acc)[4]) {
    constexpr int MI = (BN == 128) ? 4 : 2;
    int t = threadIdx.x;
    int w = t >> 6, L = t & 63, l15 = L & 15, quad = L >> 4;
    int aOff = (BN == 128) ? (w >> 1) * 64 : w * 32;
    int bOff = (BN == 128) ? (w & 1) * 64 : 0;
    int srow = L >> 2, schunk = (L & 3) * 8;   // staging: 4 lanes per row
    for (int k0 = 0; k0 < K; k0 += 32) {
        __syncthreads();    // previous tile fully consumed
#pragma unroll
        for (int j = 0; j < 2; ++j) {
            int g = w * 2 + j;
            GLDS16(A + (size_t)(aTile + g * 16 + srow) * K + k0 + schunk,
                   &As[g * 16][0]);
        }
#pragma unroll
        for (int j = 0; j < BN / 64; ++j) {
            int g = (BN == 128) ? (w * 2 + j) : w;
            GLDS16(Bt + (size_t)(bTile + g * 16 + srow) * K + k0 + schunk,
                   &Bs[g * 16][0]);
        }
        __syncthreads();    // drains vmcnt: staged tile visible
        v8s a[MI], b[4];
#pragma unroll
        for (int i = 0; i < MI; ++i) a[i] = *(const v8s*)&As[aOff + i * 16 + l15][quad * 8];
#pragma unroll
        for (int j = 0; j < 4; ++j) b[j] = *(const v8s*)&Bs[bOff + j * 16 + l15][quad * 8];
#pragma unroll
        for (int i = 0; i < MI; ++i)
#pragma unroll
            for (int j = 0; j < 4; ++j)
                acc[i][j] = SWAP
                    ? __builtin_amdgcn_mfma_f32_16x16x32_bf16(b[j], a[i], acc[i][j], 0, 0, 0)
                    : __builtin_amdgcn_mfma_f32_16x16x32_bf16(a[i], b[j], acc[i][j], 0, 0, 0);
    }
}

// ---------------- Fused GEMM -> q_h [b][h][seq][64] + K/V in MFMA-FRAGMENT order --
// k_frag/v_frag layout: [bh][tile(32)][region(8)][lane(64)][8 shorts]
__global__ __launch_bounds__(256) void gemm_qkv_kernel(const unsigned short* __restrict__ A,
                                                       const unsigned short* __restrict__ Bt,
                                                       unsigned short* __restrict__ q_h,
                                                       unsigned short* __restrict__ k_frag,
                                                       unsigned short* __restrict__ v_frag) {
    __shared__ __align__(16) unsigned short As[128][32];
    __shared__ __align__(16) unsigned short Bs[128][32];
    int t = threadIdx.x, w = t >> 6, L = t & 63, l15 = L & 15, quad = L >> 4;
    int aTile = blockIdx.y * 128, bTile = blockIdx.x * 128;
    int aOff = (w >> 1) * 64, bOff = (w & 1) * 64;
    v4f acc[4][4] = {};
    if (bTile < 2048) {
        mm_core2<128, true>(A, Bt, DIM, aTile, bTile, As, Bs, acc);
        float sc = (bTile < 1024) ? SCALE_LOG2E : 1.0f;   // uniform per block
#pragma unroll
        for (int j = 0; j < 4; ++j) {
            int col = bTile + bOff + j * 16 + quad * 4;   // 4 consecutive d
            int c = col & 1023;
            int h = c >> 6, d = c & 63;
            int half = d >> 5, Lhi = (d >> 3) & 3, jj = d & 7;
#pragma unroll
            for (int i = 0; i < 4; ++i) {
                int m = aTile + aOff + i * 16 + l15;
                int b = m >> 11, seq = m & 2047;
                ushort4 o;
                o.x = f2bf(acc[i][j][0] * sc); o.y = f2bf(acc[i][j][1] * sc);
                o.z = f2bf(acc[i][j][2] * sc); o.w = f2bf(acc[i][j][3] * sc);
                if (col < 1024) {
                    *(ushort4*)(q_h + (((size_t)(b * 16 + h)) * SEQ + seq) * 64 + d) = o;
                } else {
                    int kT = seq >> 6, jt = (seq >> 4) & 3, L15 = seq & 15;
                    size_t off = ((((size_t)(b * 16 + h) * 32 + kT) * 8 + (jt * 2 + half)) * 64
                                  + (Lhi * 16 + L15)) * 8 + jj;
                    *(ushort4*)(k_frag + off) = o;
                }
            }
        }
    } else {
        mm_core2<128, false>(A, Bt, DIM, aTile, bTile, As, Bs, acc);
#pragma unroll
        for (int j = 0; j < 4; ++j) {
            int c = bTile + bOff + j * 16 + l15 - 2048;
            int h = c >> 6, d = c & 63;
            int dt = d >> 4, L15v = d & 15;
#pragma unroll
            for (int i = 0; i < 4; ++i) {
                int m0 = aTile + aOff + i * 16 + quad * 4;   // 4 consecutive seq
                int b = m0 >> 11, seq0 = m0 & 2047;
                int vT = seq0 >> 6, half = (seq0 >> 5) & 1, Lhi = (seq0 >> 3) & 3, jv = seq0 & 7;
                ushort4 o;
                o.x = f2bf(acc[i][j][0]); o.y = f2bf(acc[i][j][1]);
                o.z = f2bf(acc[i][j][2]); o.w = f2bf(acc[i][j][3]);
                size_t off = ((((size_t)(b * 16 + h) * 32 + vT) * 8 + (dt * 2 + half)) * 64
                              + (Lhi * 16 + L15v)) * 8 + jv;
                *(ushort4*)(v_frag + off) = o;
            }
        }
    }
}

// ---------------- Final GEMM + bias, f32 out (BN=64, BK=32, C^T) ------
__global__ __launch_bounds__(256) void gemm_out_kernel(const unsigned short* __restrict__ A,
                                                       const unsigned short* __restrict__ Bt,
                                                       const float* __restrict__ bias,
                                                       float* __restrict__ C) {
    __shared__ __align__(16) unsigned short As[128][32];
    __shared__ __align__(16) unsigned short Bs[64][32];
    int t = threadIdx.x, w = t >> 6, L = t & 63, l15 = L & 15, quad = L >> 4;
    int aTile = blockIdx.y * 128, bTile = blockIdx.x * 64;
    v4f acc[2][4] = {};
    mm_core2<64, true>(A, Bt, DIM, aTile, bTile, As, Bs, acc);
#pragma unroll
    for (int j = 0; j < 4; ++j) {
        int n = bTile + j * 16 + quad * 4;    // 4 consecutive cols
        float4 bv = *(const float4*)(bias + n);
#pragma unroll
        for (int i = 0; i < 2; ++i) {
            int m = aTile + w * 32 + i * 16 + l15;
            float4 o = make_float4(acc[i][j][0] + bv.x, acc[i][j][1] + bv.y,
                                   acc[i][j][2] + bv.z, acc[i][j][3] + bv.w);
            *(float4*)(C + (size_t)m * DIM + n) = o;
        }
    }
}

// ---------------- MFMA flash attention v8 (REVERTED from v9): fragment-direct ----
// 512 blocks x 4 waves x 32 Q rows, launch_bounds(256,2): VGPR 100, no spill.
// K/V pre-stored in MFMA-fragment order -> per-wave coalesced v8s loads
// (base + lane*16B) straight from L1/L2. No K/V LDS, no DMA, no __syncthreads
// in the loop. kf(t+1) register-prefetched (ping-pong, 2x unroll).
// v9 lesson: fragment state (kA/kB/vf = 96 VGPR) is invariant in Q-rows/wave;
// halving rows under launch_bounds(256,4) spilled to scratch (468 MB writes).
__global__ __launch_bounds__(256, 2) void attn_kernel(const unsigned short* __restrict__ q_h,
                                                      const unsigned short* __restrict__ k_frag,
                                                      const unsigned short* __restrict__ v_frag,
                                                      unsigned short* __restrict__ ao) {
    __shared__ __align__(16) unsigned short Pld[4][2][16 * 72];   // 18 KB, wave-private
    int bid = blockIdx.x;
    int wg = (bid & 7) * 64 + (bid >> 3);   // XCD-contiguous remap (512 = 8*64)
    int qt = wg & 15, h = (wg >> 4) & 15, b = wg >> 8;
    int bh = b * HEADS + h;
    int w = threadIdx.x >> 6;
    int L = threadIdx.x & 63, l15 = L & 15, quad = L >> 4;

    const unsigned short* qp = q_h + ((size_t)bh * SEQ + qt * 128 + w * 32 + l15) * 64 + quad * 8;
    v8s qf[2][2];
    qf[0][0] = *(const v8s*)(qp);
    qf[0][1] = *(const v8s*)(qp + 32);
    qf[1][0] = *(const v8s*)(qp + 16 * 64);
    qf[1][1] = *(const v8s*)(qp + 16 * 64 + 32);

    // per-lane fragment bases: tile stride 4096 shorts, region stride 512
    const unsigned short* kb = k_frag + (size_t)bh * 32 * 4096 + (size_t)L * 8;
    const unsigned short* vb = v_frag + (size_t)bh * 32 * 4096 + (size_t)L * 8;

    v4f o[2][4] = {};
    v4f lacc[2] = {};
    const short ob = (short)0x3F80;   // bf16 1.0
    const v8s ones = {ob, ob, ob, ob, ob, ob, ob, ob};

    v8s kA[4][2], kB[4][2], vf[4][2];
    // prologue: kf tile 0 -> kA
#pragma unroll
    for (int jt = 0; jt < 4; ++jt) {
        kA[jt][0] = *(const v8s*)(kb + (jt * 2 + 0) * 512);
        kA[jt][1] = *(const v8s*)(kb + (jt * 2 + 1) * 512);
    }

#define ATTN_BODY(T, KC, KN)                                                          \
    {                                                                                 \
        const unsigned short* vt_ = vb + (size_t)(T) * 4096;                          \
        _Pragma("unroll")                                                             \
        for (int dt = 0; dt < 4; ++dt) {                                              \
            vf[dt][0] = *(const v8s*)(vt_ + (dt * 2 + 0) * 512);                      \
            vf[dt][1] = *(const v8s*)(vt_ + (dt * 2 + 1) * 512);                      \
        }                                                                             \
        if ((T) + 1 < SEQ / 64) {                                                     \
            const unsigned short* kt_ = kb + (size_t)((T) + 1) * 4096;                \
            _Pragma("unroll")                                                         \
            for (int jt = 0; jt < 4; ++jt) {                                          \
                KN[jt][0] = *(const v8s*)(kt_ + (jt * 2 + 0) * 512);                  \
                KN[jt][1] = *(const v8s*)(kt_ + (jt * 2 + 1) * 512);                  \
            }                                                                         \
        }                                                                             \
        v4f s[2][4] = {};                                                             \
        __builtin_amdgcn_s_setprio(1);                                                \
        _Pragma("unroll")                                                             \
        for (int m = 0; m < 2; ++m)                                                   \
            _Pragma("unroll")                                                         \
            for (int jt = 0; jt < 4; ++jt) {                                          \
                s[m][jt] = __builtin_amdgcn_mfma_f32_16x16x32_bf16(KC[jt][0], qf[m][0], s[m][jt], 0, 0, 0); \
                s[m][jt] = __builtin_amdgcn_mfma_f32_16x16x32_bf16(KC[jt][1], qf[m][1], s[m][jt], 0, 0, 0); \
            }                                                                         \
        __builtin_amdgcn_s_setprio(0);                                                \
        _Pragma("unroll")                                                             \
        for (int m = 0; m < 2; ++m)                                                   \
            _Pragma("unroll")                                                         \
            for (int jt = 0; jt < 4; ++jt) {                                          \
                float p0 = fast_exp2(s[m][jt][0]);                                    \
                float p1 = fast_exp2(s[m][jt][1]);                                    \
                float p2 = fast_exp2(s[m][jt][2]);                                    \
                float p3 = fast_exp2(s[m][jt][3]);                                    \
                uint2 pk;                                                             \
                pk.x = pk_bf2(p1, p0);                                                \
                pk.y = pk_bf2(p3, p2);                                                \
                *(uint2*)&Pld[w][m][l15 * 72 + jt * 16 + quad * 4] = pk;              \
            }                                                                         \
        _Pragma("unroll")                                                             \
        for (int m = 0; m < 2; ++m) {                                                 \
            v8s pb0 = *(const v8s*)&Pld[w][m][l15 * 72 + quad * 8];                   \
            v8s pb1 = *(const v8s*)&Pld[w][m][l15 * 72 + 32 + quad * 8];              \
            __builtin_amdgcn_s_setprio(1);                                            \
            _Pragma("unroll")                                                         \
            for (int dt = 0; dt < 4; ++dt) {                                          \
                o[m][dt] = __builtin_amdgcn_mfma_f32_16x16x32_bf16(vf[dt][0], pb0, o[m][dt], 0, 0, 0); \
                o[m][dt] = __builtin_amdgcn_mfma_f32_16x16x32_bf16(vf[dt][1], pb1, o[m][dt], 0, 0, 0); \
            }                                                                         \
            lacc[m] = __builtin_amdgcn_mfma_f32_16x16x32_bf16(ones, pb0, lacc[m], 0, 0, 0); \
            lacc[m] = __builtin_amdgcn_mfma_f32_16x16x32_bf16(ones, pb1, lacc[m], 0, 0, 0); \
            __builtin_amdgcn_s_setprio(0);                                            \
        }                                                                             \
    }

    for (int t = 0; t < SEQ / 64; t += 2) {
        ATTN_BODY(t, kA, kB);
        ATTN_BODY(t + 1, kB, kA);
    }
#undef ATTN_BODY

#pragma unroll
    for (int m = 0; m < 2; ++m) {
        float inv = 1.f / lacc[m][0];
        int rowg = b * SEQ + qt * 128 + w * 32 + m * 16 + l15;
#pragma unroll
        for (int dt = 0; dt < 4; ++dt) {
            ushort4 ov;
            ov.x = f2bf(o[m][dt][0] * inv);
            ov.y = f2bf(o[m][dt][1] * inv);
            ov.z = f2bf(o[m][dt][2] * inv);
            ov.w = f2bf(o[m][dt][3] * inv);
            *(ushort4*)(ao + (size_t)rowg * DIM + h * 64 + dt * 16 + quad * 4) = ov;
        }
    }
}

extern "C" void kernel_launch(void* const* d_in, const int* in_sizes, int n_in,
                              void* d_out, int out_size, void* d_ws, size_t ws_size,
                              hipStream_t stream) {
    const float* x     = (const float*)d_in[0];
    const float* gamma = (const float*)d_in[1];
    const float* beta  = (const float*)d_in[2];
    const float* Wqk   = (const float*)d_in[3];
    const float* Wv    = (const float*)d_in[4];
    const float* Wout  = (const float*)d_in[5];
    const float* bout  = (const float*)d_in[6];
    float* out = (float*)d_out;

    unsigned short* ws = (unsigned short*)d_ws;
    unsigned short* xn     = ws;                            // 4096*1024
    unsigned short* Wt_qk  = xn + (size_t)ROWS * DIM;       // 2048*1024
    unsigned short* Wt_v   = Wt_qk + (size_t)2048 * DIM;    // 1024*1024 (contiguous after qk)
    unsigned short* Wt_o   = Wt_v + (size_t)DIM * DIM;      // 1024*1024
    unsigned short* q_h    = Wt_o + (size_t)DIM * DIM;      // 4096*1024
    unsigned short* k_frag = q_h + (size_t)ROWS * DIM;      // 4096*1024 (fragment order)
    unsigned short* v_frag = k_frag + (size_t)ROWS * DIM;   // 4096*1024 (fragment order)
    unsigned short* ao     = v_frag + (size_t)ROWS * DIM;   // 4096*1024

    ln_tr_kernel<<<ROWS + 1024, 256, 0, stream>>>(x, gamma, beta, xn,
                                                  Wqk, Wv, Wout, Wt_qk, Wt_v, Wt_o);
    gemm_qkv_kernel<<<dim3(3072 / 128, ROWS / 128), 256, 0, stream>>>(xn, Wt_qk, q_h, k_frag, v_frag);
    attn_kernel<<<dim3(SEQ / 128 * HEADS * BATCH), 256, 0, stream>>>(q_h, k_frag, v_frag, ao);
    gemm_out_kernel<<<dim3(DIM / 64, ROWS / 128), 256, 0, stream>>>(ao, Wt_o, bout, out);
}